// Round 9
// baseline (1209.718 us; speedup 1.0000x reference)
//
#include <hip/hip_runtime.h>

// B=8, T=8, S=500 (padded 512), F_IN=32, F=F_OUT=64, K=3, L=3
#define BB 8
#define TT 8
#define SS 500
#define SP 512
#define FIN 32
#define FF 64
#define KT 1536        // 24 * 64 : Abig row length  (k = t'*192 + bp*64 + j)
#define LROW_S 136     // smm LDS row stride in shorts (BK=128 + 8 pad)
#define HROW 200       // hmix Bs row stride in shorts (192 + 8)
#define WROW 196       // hmix W row stride in floats (192 + 4)
#define OROW 520       // hmix Ob row stride in shorts (512 + 8)
#define NB  512        // grid size; 2 blocks/CU x 256 CU -> all co-resident

typedef short bf16x8 __attribute__((ext_vector_type(8)));
typedef float floatx4 __attribute__((ext_vector_type(4)));

__device__ __forceinline__ unsigned f2bf(float x) {
    unsigned u = __builtin_bit_cast(unsigned, x);
    return (u + 0x7FFFu + ((u >> 16) & 1u)) >> 16;   // RNE bf16 in low 16
}
__device__ __forceinline__ float bf2f(unsigned short h) {
    unsigned u = ((unsigned)h) << 16;
    return __builtin_bit_cast(float, u);
}
__device__ __forceinline__ float ftanh(float x) {
    float ax = fabsf(x);
    float e = __expf(-2.f * ax);
    float r = (1.f - e) * __builtin_amdgcn_rcpf(1.f + e);
    return copysignf(r, x);
}

__device__ __forceinline__ void ctab(int m, float s0, float s1, float s2, float s3,
                                     float& c0, float& c1, float& c2) {
    c0 = 0.f; c1 = 0.f; c2 = 0.f;
    switch (m) {
        case 0: c0 = 1.f; c1 = s0; c2 = s0 * s0; break;
        case 1: c1 = s1; c2 = 2.f * s0 * s1; break;
        case 2: c2 = s1 * s1; break;
        case 3: c1 = s2; c2 = 2.f * s0 * s2; break;
        case 4: c1 = s3; c2 = 2.f * (s0 * s3 + s1 * s2); break;
        case 5: c2 = 2.f * s1 * s3; break;
        case 6: c2 = s2 * s2; break;
        case 7: c2 = 2.f * s2 * s3; break;
        case 8: c2 = s3 * s3; break;
    }
}

// Software grid barrier: generation-based, agent scope, bounded spin.
// Safe to reuse: cnt reset (relaxed) is ordered before gen release-increment.
__device__ __forceinline__ void gbar(unsigned* bar) {
    __threadfence();                 // release this block's writes (agent scope)
    __syncthreads();
    if (threadIdx.x == 0) {
        unsigned* cnt = bar;
        unsigned* gen = bar + 1;
        unsigned g = __hip_atomic_load(gen, __ATOMIC_RELAXED, __HIP_MEMORY_SCOPE_AGENT);
        unsigned a = __hip_atomic_fetch_add(cnt, 1u, __ATOMIC_ACQ_REL, __HIP_MEMORY_SCOPE_AGENT);
        if (a == (unsigned)(NB - 1)) {
            __hip_atomic_store(cnt, 0u, __ATOMIC_RELAXED, __HIP_MEMORY_SCOPE_AGENT);
            __hip_atomic_fetch_add(gen, 1u, __ATOMIC_RELEASE, __HIP_MEMORY_SCOPE_AGENT);
        } else {
            unsigned spins = 0;
            while (__hip_atomic_load(gen, __ATOMIC_ACQUIRE, __HIP_MEMORY_SCOPE_AGENT) == g) {
                __builtin_amdgcn_s_sleep(2);
                if (++spins > (1u << 24)) break;   // escape hatch: fail clean, never hang
            }
        }
    }
    __syncthreads();
    __threadfence();                 // acquire other blocks' writes
}

// ---------------------------------------------------------------------------
// mega_k: all phases, one NORMAL launch (graph-capturable). Grid 512 x 256.
// LDS union 77632 B -> 2 blocks/CU -> all 512 blocks co-resident (by
// occupancy arithmetic, not cooperative API). Phases separated by gbar();
// bodies are the R4-verified kernels verbatim, grid-stride mapped.
// ---------------------------------------------------------------------------
__global__ void __launch_bounds__(256, 2)
mega_k(const float* __restrict__ x,   const float* __restrict__ At,
       const float* __restrict__ As,  const float* __restrict__ sc,
       const float* __restrict__ H,   const float* __restrict__ W1,
       const float* __restrict__ b1,  const float* __restrict__ W2,
       const float* __restrict__ b2,  const float* __restrict__ merge,
       unsigned short* __restrict__ Asb,  unsigned short* __restrict__ AsbT,
       unsigned short* __restrict__ Asqb, unsigned short* __restrict__ HcT,
       float* __restrict__ CtT,
       unsigned short* __restrict__ xfT0, unsigned short* __restrict__ xfT1,
       unsigned short* __restrict__ Abig0, unsigned short* __restrict__ Abig1,
       float* __restrict__ out, unsigned* bar) {
    __shared__ int4 smem4[4852];                  // 77632 B union
    char* smem = (char*)smem4;

    int bid = blockIdx.x;
    int tid = threadIdx.x;

    // ======================= P0: setup =======================
    for (int c = bid; c < 2993; c += NB) {
        if (c < 512) {
            // ---- lin1 path (LDS carve: Xs[64][33] Wl1[32][64] Ot[64][65] bl[64])
            float* Xs  = (float*)smem;            // 8448 B
            float* Wl1 = (float*)(smem + 8448);   // 8192 B
            float* Ot  = (float*)(smem + 16640);  // 16640 B
            float* bl  = (float*)(smem + 33280);  // 256 B
            int bt = c >> 3, s0 = (c & 7) * 64;
            int b = bt >> 3, t = bt & 7;

            for (int i = tid; i < FIN * FF; i += 256) { int f = i >> 5, j = i & 31; Wl1[j * 64 + f] = W1[i]; }
            if (tid < FF) bl[tid] = b1[tid];
            const float* xb = x + (size_t)bt * SS * FIN;
            #pragma unroll
            for (int i = 0; i < 8; ++i) {
                int lin = i * 256 + tid; int r = lin >> 5, j = lin & 31;
                int s = s0 + r;
                Xs[r * 33 + j] = (s < SS) ? xb[(size_t)s * FIN + j] : 0.f;
            }
            __syncthreads();
            int f = tid & 63, sq = tid >> 6;
            for (int i = 0; i < 16; ++i) {
                int r = sq * 16 + i;
                float acc = bl[f];
                #pragma unroll
                for (int j = 0; j < FIN; ++j) acc += Xs[r * 33 + j] * Wl1[j * 64 + f];
                Ot[r * 65 + f] = (s0 + r < SS) ? acc : 0.f;
            }
            __syncthreads();
            // Abig0 slot0 write (row-major)
            #pragma unroll
            for (int it = 0; it < 2; ++it) {
                int idx = it * 256 + tid;
                int row = idx >> 3, cc = idx & 7;
                int4 w;
                unsigned short tmp[8];
                #pragma unroll
                for (int q = 0; q < 8; ++q) tmp[q] = (unsigned short)f2bf(Ot[row * 65 + cc * 8 + q]);
                w.x = tmp[0] | (tmp[1] << 16); w.y = tmp[2] | (tmp[3] << 16);
                w.z = tmp[4] | (tmp[5] << 16); w.w = tmp[6] | (tmp[7] << 16);
                *(int4*)(Abig0 + (size_t)(b * SP + s0 + row) * KT + t * 192 + cc * 8) = w;
            }
            // transposed write
            {
                int ff = tid >> 2, scol = (tid & 3) * 16;
                unsigned short tmp[16];
                #pragma unroll
                for (int i = 0; i < 16; ++i) tmp[i] = (unsigned short)f2bf(Ot[(scol + i) * 65 + ff]);
                unsigned short* dp = xfT0 + ((size_t)bt * FF + ff) * SP + s0 + scol;
                #pragma unroll
                for (int q = 0; q < 2; ++q) {
                    int4 w;
                    w.x = tmp[q*8+0] | (tmp[q*8+1] << 16); w.y = tmp[q*8+2] | (tmp[q*8+3] << 16);
                    w.z = tmp[q*8+4] | (tmp[q*8+5] << 16); w.w = tmp[q*8+6] | (tmp[q*8+7] << 16);
                    *(int4*)(dp + q * 8) = w;
                }
            }
            __syncthreads();
        } else {
            // ---- prep path
            int idx = (c - 512) * 256 + tid;
            if (idx < 262144) {
                int s = idx >> 9, k = idx & 511;
                Asb[idx] = (s < SS && k < SS) ? (unsigned short)f2bf(As[(size_t)s * SS + k]) : 0;
            } else if (idx < 524288) {
                int r = idx - 262144;
                int j = r >> 9, k = r & 511;
                AsbT[r] = (j < SS && k < SS) ? (unsigned short)f2bf(As[(size_t)k * SS + j]) : 0;
            } else {
                int r = idx - 524288;
                if (r < 110592) {
                    int l = r / 36864;
                    int r2 = r - l * 36864;
                    int row = r2 / 192;
                    int col = r2 - row * 192;
                    int p = row >> 6, f = row & 63;
                    int bp = col >> 6, j = col & 63;
                    float s0 = sc[0], s1 = sc[1], s2 = sc[2], s3 = sc[3];
                    float c0, c1, c2;
                    ctab(p * 3 + bp, s0, s1, s2, s3, c0, c1, c2);
                    float val = c0 * H[((size_t)(l * 3 + 0) * 64 + j) * 64 + f]
                              + c1 * H[((size_t)(l * 3 + 1) * 64 + j) * 64 + f]
                              + c2 * H[((size_t)(l * 3 + 2) * 64 + j) * 64 + f];
                    HcT[r] = (unsigned short)f2bf(val);
                } else if (r < 110784) {
                    int i2 = r - 110592;
                    int pt = i2 >> 3, t = i2 & 7;
                    int p = pt >> 3, tp = pt & 7;
                    float val;
                    if (p == 0) val = (t == tp) ? 1.f : 0.f;
                    else if (p == 1) val = At[t * 8 + tp];
                    else {
                        val = 0.f;
                        #pragma unroll
                        for (int kk = 0; kk < 8; ++kk) val += At[t * 8 + kk] * At[kk * 8 + tp];
                    }
                    CtT[i2] = val;
                }
            }
        }
    }
    gbar(bar);

    // ======================= P1: prep2 (Asqb = As@As) =======================
    for (int v = bid; v < 256; v += NB) {
        int wave = tid >> 6, lane = tid & 63;
        int l16 = lane & 15, quad = lane >> 4;
        int st = v & 31, ct = v >> 5;

        const unsigned short* ap = Asb + (size_t)(st * 16 + l16) * SP + quad * 8;
        const unsigned short* bp = AsbT + (size_t)(ct * 64 + wave * 16 + l16) * SP + quad * 8;
        floatx4 acc = {};
        #pragma unroll 4
        for (int k0 = 0; k0 < SP; k0 += 32)
            acc = __builtin_amdgcn_mfma_f32_16x16x32_bf16(*(const bf16x8*)(ap + k0),
                                                          *(const bf16x8*)(bp + k0), acc, 0, 0, 0);
        int j = ct * 64 + wave * 16 + l16;
        int i0 = st * 16 + quad * 4;
        #pragma unroll
        for (int r = 0; r < 4; ++r)
            Asqb[(size_t)(i0 + r) * SP + j] = (unsigned short)f2bf(acc[r]);
    }
    gbar(bar);

    // ======================= layers =======================
    unsigned short* xfc = xfT0; unsigned short* xfn = xfT1;
    unsigned short* Ac  = Abig0; unsigned short* An = Abig1;

    for (int l = 0; l < 3; ++l) {
        // ---- smm (R4): u1 = As.xf, u2 = As^2.xf -> Ac slots 1,2
        for (int v = bid; v < 512; v += NB) {
            unsigned short* A1 = (unsigned short*)smem;
            unsigned short* A2 = A1 + 64 * LROW_S;
            unsigned short* Bt = A2 + 64 * LROW_S;

            int wave = tid >> 6, lane = tid & 63;
            int l16 = lane & 15, quad = lane >> 4;
            int m0 = (v & 7) * 64, bt = v >> 3;
            int b = bt >> 3, t = bt & 7;

            const unsigned short* a1g = Asb + (size_t)m0 * SP;
            const unsigned short* a2g = Asqb + (size_t)m0 * SP;
            const unsigned short* bg  = xfc + (size_t)bt * FF * SP;

            floatx4 acc1[4] = {}, acc2[4] = {};

            for (int k0 = 0; k0 < SP; k0 += 128) {
                __syncthreads();
                #pragma unroll
                for (int it = 0; it < 4; ++it) {
                    int idx = it * 256 + tid;
                    int row = idx >> 4, cc = idx & 15;
                    int4 v1 = *(const int4*)(a1g + (size_t)row * SP + k0 + cc * 8);
                    int4 v2 = *(const int4*)(a2g + (size_t)row * SP + k0 + cc * 8);
                    int4 vb = *(const int4*)(bg  + (size_t)row * SP + k0 + cc * 8);
                    *(int4*)&A1[row * LROW_S + cc * 8] = v1;
                    *(int4*)&A2[row * LROW_S + cc * 8] = v2;
                    *(int4*)&Bt[row * LROW_S + cc * 8] = vb;
                }
                __syncthreads();
                #pragma unroll
                for (int ks = 0; ks < 4; ++ks) {
                    bf16x8 af1 = *(const bf16x8*)&A1[(wave * 16 + l16) * LROW_S + ks * 32 + quad * 8];
                    bf16x8 af2 = *(const bf16x8*)&A2[(wave * 16 + l16) * LROW_S + ks * 32 + quad * 8];
                    #pragma unroll
                    for (int nt = 0; nt < 4; ++nt) {
                        bf16x8 bf = *(const bf16x8*)&Bt[(nt * 16 + l16) * LROW_S + ks * 32 + quad * 8];
                        acc1[nt] = __builtin_amdgcn_mfma_f32_16x16x32_bf16(af1, bf, acc1[nt], 0, 0, 0);
                        acc2[nt] = __builtin_amdgcn_mfma_f32_16x16x32_bf16(af2, bf, acc2[nt], 0, 0, 0);
                    }
                }
            }

            __syncthreads();
            #pragma unroll
            for (int nt = 0; nt < 4; ++nt)
                #pragma unroll
                for (int r = 0; r < 4; ++r) {
                    A1[(wave * 16 + quad * 4 + r) * LROW_S + nt * 16 + l16] = (unsigned short)f2bf(acc1[nt][r]);
                    A2[(wave * 16 + quad * 4 + r) * LROW_S + nt * 16 + l16] = (unsigned short)f2bf(acc2[nt][r]);
                }
            __syncthreads();
            int row = wave * 16 + (lane >> 2);
            int c2 = (lane & 3) * 2;
            #pragma unroll
            for (int q = 0; q < 2; ++q) {
                int cc = c2 + q;
                int4 v1 = *(const int4*)&A1[row * LROW_S + cc * 8];
                int4 v2 = *(const int4*)&A2[row * LROW_S + cc * 8];
                size_t base = (size_t)(b * SP + m0 + row) * KT + t * 192;
                *(int4*)(Ac + base + 64 + cc * 8)  = v1;
                *(int4*)(Ac + base + 128 + cc * 8) = v2;
            }
        }
        gbar(bar);

        // ---- hmix (R4): A direct from global, HcT staged; wflag / fused zred
        for (int v = bid; v < 512; v += NB) {
            const unsigned short* HcT_l = HcT + (size_t)l * 36864;
            int wflag = (l < 2) ? 1 : 0;

            unsigned short* Bs  = (unsigned short*)smem;
            float* Wl           = (float*)smem;                    // [64][196]
            unsigned short* Ob  = (unsigned short*)(smem + 50176); // [8][520]
            float* W2l          = (float*)(smem + 50176);          // [64][65]
            float* zt           = (float*)(smem + 66816);          // [8][65]
            float* CtS          = (float*)(smem + 76800);          // [192]
            float* mlS          = (float*)(smem + 77568);          // [8]

            int wave = tid >> 6, lane = tid & 63;
            int l16 = lane & 15, quad = lane >> 4;
            int wm = wave & 1, wn = wave >> 1;
            int s0 = (v & 63) * 8, b = v >> 6;

            if (tid < 192) CtS[tid] = CtT[tid];
            if (tid < 8) mlS[tid] = merge[tid];

            bf16x8 afr[2][6];
            {
                const unsigned short* abase =
                    Ac + (size_t)(b * SP + s0 + (l16 & 7)) * KT + quad * 8;
                #pragma unroll
                for (int mt = 0; mt < 2; ++mt) {
                    int tp = (wm * 2 + mt) * 2 + (l16 >> 3);
                    #pragma unroll
                    for (int ks = 0; ks < 6; ++ks)
                        afr[mt][ks] = *(const bf16x8*)(abase + tp * 192 + ks * 32);
                }
            }

            {
                int br = tid >> 3, bc = tid & 7;
                #pragma unroll
                for (int it = 0; it < 6; ++it) {
                    int row = it * 32 + br;
                    const unsigned short* hp = HcT_l + (size_t)row * 192;
                    #pragma unroll
                    for (int j = 0; j < 3; ++j) {
                        int cc = bc + j * 8;
                        *(int4*)&Bs[row * HROW + cc * 8] = *(const int4*)(hp + cc * 8);
                    }
                }
            }
            __syncthreads();

            floatx4 acc[2][6] = {};
            #pragma unroll
            for (int ks = 0; ks < 6; ++ks) {
                bf16x8 bfr[6];
                #pragma unroll
                for (int nt = 0; nt < 6; ++nt)
                    bfr[nt] = *(const bf16x8*)&Bs[((wn * 6 + nt) * 16 + l16) * HROW + ks * 32 + quad * 8];
                #pragma unroll
                for (int mt = 0; mt < 2; ++mt)
                    #pragma unroll
                    for (int nt = 0; nt < 6; ++nt)
                        acc[mt][nt] = __builtin_amdgcn_mfma_f32_16x16x32_bf16(afr[mt][ks], bfr[nt], acc[mt][nt], 0, 0, 0);
            }

            __syncthreads();   // Bs dead; Wl aliases it

            #pragma unroll
            for (int mt = 0; mt < 2; ++mt)
                #pragma unroll
                for (int nt = 0; nt < 6; ++nt) {
                    int col = (wn * 6 + nt) * 16 + l16;
                    #pragma unroll
                    for (int r = 0; r < 4; ++r) {
                        int fr = quad * 4 + r;
                        int tp = (wm * 2 + mt) * 2 + (fr >> 3);
                        int srow = fr & 7;
                        Wl[(tp * 8 + srow) * WROW + col] = acc[mt][nt][r];
                    }
                }
            if (!wflag) {
                for (int i = tid; i < 4096; i += 256) { int f = i >> 6, j = i & 63; W2l[j * 65 + f] = W2[i]; }
            }
            __syncthreads();

            int f = tid & 63, sg = tid >> 6;
            float th[8][2];
            {
                float o[8][2] = {};
                #pragma unroll
                for (int pt = 0; pt < 24; ++pt) {
                    int tp = pt & 7, p = pt >> 3;
                    float w0 = Wl[(tp * 8 + sg * 2 + 0) * WROW + p * 64 + f];
                    float w1 = Wl[(tp * 8 + sg * 2 + 1) * WROW + p * 64 + f];
                    #pragma unroll
                    for (int t = 0; t < 8; ++t) {
                        float cv = CtS[pt * 8 + t];
                        o[t][0] += cv * w0;
                        o[t][1] += cv * w1;
                    }
                }
                #pragma unroll
                for (int t = 0; t < 8; ++t) {
                    th[t][0] = ftanh(o[t][0]);
                    th[t][1] = ftanh(o[t][1]);
                }
            }

            if (wflag) {
                #pragma unroll
                for (int t = 0; t < 8; ++t) {
                    Ob[(sg * 2 + 0) * OROW + t * 64 + f] = (unsigned short)f2bf(th[t][0]);
                    Ob[(sg * 2 + 1) * OROW + t * 64 + f] = (unsigned short)f2bf(th[t][1]);
                }
                __syncthreads();
                #pragma unroll
                for (int it = 0; it < 2; ++it) {
                    int idx = it * 256 + tid;        // [0,512)
                    int row = idx >> 6, cc = idx & 63;
                    int t = cc >> 3, c8 = cc & 7;
                    int4 w = *(const int4*)&Ob[row * OROW + cc * 8];
                    *(int4*)(An + (size_t)(b * SP + s0 + row) * KT + t * 192 + c8 * 8) = w;
                }
                #pragma unroll
                for (int it = 0; it < 2; ++it) {
                    int u = it * 256 + tid;          // [0,512)
                    int t = u >> 6, ff = u & 63;
                    unsigned short tmp[8];
                    #pragma unroll
                    for (int sl = 0; sl < 8; ++sl) tmp[sl] = Ob[sl * OROW + t * 64 + ff];
                    int4 w;
                    w.x = tmp[0] | (tmp[1] << 16); w.y = tmp[2] | (tmp[3] << 16);
                    w.z = tmp[4] | (tmp[5] << 16); w.w = tmp[6] | (tmp[7] << 16);
                    *(int4*)(xfn + ((size_t)(b * 8 + t) * FF + ff) * SP + s0) = w;
                }
            } else {
                float z0 = 0.f, z1 = 0.f;
                #pragma unroll
                for (int t = 0; t < 8; ++t) {
                    z0 += mlS[t] * th[t][0];
                    z1 += mlS[t] * th[t][1];
                }
                zt[(sg * 2 + 0) * 65 + f] = z0;
                zt[(sg * 2 + 1) * 65 + f] = z1;
                __syncthreads();
                float msum = 0.f;
                #pragma unroll
                for (int t = 0; t < 8; ++t) msum += mlS[t];
                float bv = b2[f] * msum;
                #pragma unroll
                for (int r = 0; r < 2; ++r) {
                    int s = s0 + sg * 2 + r;
                    if (s < SS) {
                        float accv = bv;
                        #pragma unroll
                        for (int j = 0; j < FF; ++j) accv += zt[(sg * 2 + r) * 65 + j] * W2l[j * 65 + f];
                        out[((size_t)b * SS + s) * FF + f] = accv;
                    }
                }
            }
        }
        if (l < 2) gbar(bar);

        unsigned short* t1 = xfc; xfc = xfn; xfn = t1;
        unsigned short* t2 = Ac;  Ac = An;   An = t2;
    }
}

// ---------------------------------------------------------------------------
extern "C" void kernel_launch(void* const* d_in, const int* in_sizes, int n_in,
                              void* d_out, int out_size, void* d_ws, size_t ws_size,
                              hipStream_t stream) {
    const float* x     = (const float*)d_in[0];
    const float* At    = (const float*)d_in[1];
    const float* As    = (const float*)d_in[2];
    const float* sc    = (const float*)d_in[3];
    const float* H     = (const float*)d_in[4];
    const float* W1    = (const float*)d_in[5];
    const float* b1    = (const float*)d_in[6];
    const float* W2    = (const float*)d_in[7];
    const float* b2    = (const float*)d_in[8];
    const float* merge = (const float*)d_in[9];
    float* out = (float*)d_out;

    char* ws = (char*)d_ws;
    unsigned short* Asb   = (unsigned short*)(ws + 0);          // 524288
    unsigned short* AsbT  = (unsigned short*)(ws + 524288);     // 524288
    unsigned short* Asqb  = (unsigned short*)(ws + 1048576);    // 524288
    unsigned short* HcT   = (unsigned short*)(ws + 1572864);    // 221184
    float*          CtT   = (float*)(ws + 1794048);             // 768
    unsigned*       bar   = (unsigned*)(ws + 2097152);          // 64 B barrier state
    unsigned short* xfT0  = (unsigned short*)(ws + 6291456);    // 4194304
    unsigned short* xfT1  = (unsigned short*)(ws + 10485760);   // 4194304
    unsigned short* Abig0 = (unsigned short*)(ws + 14680064);   // 12582912
    unsigned short* Abig1 = (unsigned short*)(ws + 27262976);   // 12582912

    hipMemsetAsync(bar, 0, 64, stream);   // workspace is re-poisoned between iters
    mega_k<<<NB, 256, 0, stream>>>(x, At, As, sc, H, W1, b1, W2, b2, merge,
                                   Asb, AsbT, Asqb, HcT, CtT,
                                   xfT0, xfT1, Abig0, Abig1, out, bar);
}

// Round 10
// 230.020 us; speedup vs baseline: 5.2592x; 5.2592x over previous
//
#include <hip/hip_runtime.h>

// B=8, T=8, S=500 (padded 512), F_IN=32, F=F_OUT=64, K=3, L=3
#define BB 8
#define TT 8
#define SS 500
#define SP 512
#define FIN 32
#define FF 64
#define HROW 200      // Hc LDS row stride in shorts (192 + 8)
#define WROW 196      // W row stride in floats (192 + 4)
#define OROW 520      // Ob row stride in shorts (512 + 8)
#define ABROW 1552    // Ablk row stride in shorts (1536 + 16, keeps 16B align)
#define ACROW 520     // Acomb row stride in shorts (512 + 8)

typedef short bf16x8 __attribute__((ext_vector_type(8)));
typedef float floatx4 __attribute__((ext_vector_type(4)));

__device__ __forceinline__ unsigned f2bf(float x) {
    unsigned u = __builtin_bit_cast(unsigned, x);
    return (u + 0x7FFFu + ((u >> 16) & 1u)) >> 16;   // RNE bf16 in low 16
}
__device__ __forceinline__ float ftanh(float x) {
    float ax = fabsf(x);
    float e = __expf(-2.f * ax);
    float r = (1.f - e) * __builtin_amdgcn_rcpf(1.f + e);
    return copysignf(r, x);
}

__device__ __forceinline__ void ctab(int m, float s0, float s1, float s2, float s3,
                                     float& c0, float& c1, float& c2) {
    c0 = 0.f; c1 = 0.f; c2 = 0.f;
    switch (m) {
        case 0: c0 = 1.f; c1 = s0; c2 = s0 * s0; break;
        case 1: c1 = s1; c2 = 2.f * s0 * s1; break;
        case 2: c2 = s1 * s1; break;
        case 3: c1 = s2; c2 = 2.f * s0 * s2; break;
        case 4: c1 = s3; c2 = 2.f * (s0 * s3 + s1 * s2); break;
        case 5: c2 = 2.f * s1 * s3; break;
        case 6: c2 = s2 * s2; break;
        case 7: c2 = 2.f * s2 * s3; break;
        case 8: c2 = s3 * s3; break;
    }
}

// ---------------------------------------------------------------------------
// setup_k: blocks [0,512): lin1 -> xfT only; blocks [512,...): Asb/AsbT+HcT+CtT
// ---------------------------------------------------------------------------
__global__ __launch_bounds__(256) void setup_k(const float* __restrict__ x,
                                               const float* __restrict__ W1,
                                               const float* __restrict__ b1,
                                               const float* __restrict__ As,
                                               const float* __restrict__ At,
                                               const float* __restrict__ sc,
                                               const float* __restrict__ H,
                                               unsigned short* __restrict__ Asb,
                                               unsigned short* __restrict__ AsbT,
                                               unsigned short* __restrict__ HcT,
                                               float* __restrict__ CtT,
                                               unsigned short* __restrict__ xfT) {
    int tid = threadIdx.x;
    if (blockIdx.x < 512) {
        __shared__ float Xs[64][FIN + 1];
        __shared__ float Wl[FIN][FF];
        __shared__ float Ot[64][FF + 1];
        __shared__ float bl[FF];
        int bt = blockIdx.x >> 3, s0 = (blockIdx.x & 7) * 64;

        for (int i = tid; i < FIN * FF; i += 256) { int f = i >> 5, j = i & 31; Wl[j][f] = W1[i]; }
        if (tid < FF) bl[tid] = b1[tid];
        const float* xb = x + (size_t)bt * SS * FIN;
        #pragma unroll
        for (int i = 0; i < 8; ++i) {
            int lin = i * 256 + tid; int r = lin >> 5, j = lin & 31;
            int s = s0 + r;
            Xs[r][j] = (s < SS) ? xb[(size_t)s * FIN + j] : 0.f;
        }
        __syncthreads();
        int f = tid & 63, sq = tid >> 6;
        for (int i = 0; i < 16; ++i) {
            int r = sq * 16 + i;
            float acc = bl[f];
            #pragma unroll
            for (int j = 0; j < FIN; ++j) acc += Xs[r][j] * Wl[j][f];
            Ot[r][f] = (s0 + r < SS) ? acc : 0.f;
        }
        __syncthreads();
        // transposed write: xfT[bt][f][s]
        {
            int ff = tid >> 2, scol = (tid & 3) * 16;
            unsigned short tmp[16];
            #pragma unroll
            for (int i = 0; i < 16; ++i) tmp[i] = (unsigned short)f2bf(Ot[scol + i][ff]);
            unsigned short* dp = xfT + ((size_t)bt * FF + ff) * SP + s0 + scol;
            #pragma unroll
            for (int q = 0; q < 2; ++q) {
                int4 w;
                w.x = tmp[q*8+0] | (tmp[q*8+1] << 16); w.y = tmp[q*8+2] | (tmp[q*8+3] << 16);
                w.z = tmp[q*8+4] | (tmp[q*8+5] << 16); w.w = tmp[q*8+6] | (tmp[q*8+7] << 16);
                *(int4*)(dp + q * 8) = w;
            }
        }
        return;
    }
    int idx = (blockIdx.x - 512) * 256 + tid;
    if (idx < 262144) {
        int s = idx >> 9, k = idx & 511;
        Asb[idx] = (s < SS && k < SS) ? (unsigned short)f2bf(As[(size_t)s * SS + k]) : 0;
    } else if (idx < 524288) {
        int r = idx - 262144;
        int j = r >> 9, k = r & 511;
        AsbT[r] = (j < SS && k < SS) ? (unsigned short)f2bf(As[(size_t)k * SS + j]) : 0;
    } else {
        int r = idx - 524288;
        if (r < 110592) {
            int l = r / 36864;
            int r2 = r - l * 36864;
            int row = r2 / 192;
            int col = r2 - row * 192;
            int p = row >> 6, f = row & 63;
            int bp = col >> 6, j = col & 63;
            float s0 = sc[0], s1 = sc[1], s2 = sc[2], s3 = sc[3];
            float c0, c1, c2;
            ctab(p * 3 + bp, s0, s1, s2, s3, c0, c1, c2);
            float val = c0 * H[((size_t)(l * 3 + 0) * 64 + j) * 64 + f]
                      + c1 * H[((size_t)(l * 3 + 1) * 64 + j) * 64 + f]
                      + c2 * H[((size_t)(l * 3 + 2) * 64 + j) * 64 + f];
            HcT[r] = (unsigned short)f2bf(val);
        } else if (r < 110784) {
            int i2 = r - 110592;
            int pt = i2 >> 3, t = i2 & 7;
            int p = pt >> 3, tp = pt & 7;
            float val;
            if (p == 0) val = (t == tp) ? 1.f : 0.f;
            else if (p == 1) val = At[t * 8 + tp];
            else {
                val = 0.f;
                #pragma unroll
                for (int kk = 0; kk < 8; ++kk) val += At[t * 8 + kk] * At[kk * 8 + tp];
            }
            CtT[i2] = val;
        }
    }
}

// ---------------------------------------------------------------------------
// prep2: Asqb = (As@As) bf16 [512][512]  (unchanged, R4-verified)
// ---------------------------------------------------------------------------
__global__ __launch_bounds__(256) void prep2_k(const unsigned short* __restrict__ Asb,
                                               const unsigned short* __restrict__ AsbT,
                                               unsigned short* __restrict__ Asqb) {
    int tid = threadIdx.x;
    int wave = tid >> 6, lane = tid & 63;
    int l16 = lane & 15, quad = lane >> 4;
    int st = blockIdx.x, ct = blockIdx.y;

    const unsigned short* ap = Asb + (size_t)(st * 16 + l16) * SP + quad * 8;
    const unsigned short* bp = AsbT + (size_t)(ct * 64 + wave * 16 + l16) * SP + quad * 8;
    floatx4 acc = {};
    #pragma unroll 4
    for (int k0 = 0; k0 < SP; k0 += 32)
        acc = __builtin_amdgcn_mfma_f32_16x16x32_bf16(*(const bf16x8*)(ap + k0),
                                                      *(const bf16x8*)(bp + k0), acc, 0, 0, 0);
    int j = ct * 64 + wave * 16 + l16;
    int i0 = st * 16 + quad * 4;
    #pragma unroll
    for (int r = 0; r < 4; ++r)
        Asqb[(size_t)(i0 + r) * SP + j] = (unsigned short)f2bf(acc[r]);
}

// ---------------------------------------------------------------------------
// layer_k: fused smm+hmix(+zred on last). grid (64 s-tiles of 8, 8 b).
// Phase A: Acomb=[As8;Asq8] one M=16 fragment -> u1(rows0-7),u2(rows8-15);
//          B-frags per-lane direct from xfT (its [f][s] layout IS the B pattern).
//          u0 copied from xfT. All 24 panels -> Ablk LDS [8][1552].
// Phase B: R4 hmix GEMM verbatim, A-frags from Ablk LDS, B from Hc LDS.
// Phase C: R4 temporal mix verbatim; wflag -> xfT_out; else fused zredlin2.
// LDS: Ablk 24832 | region2 76800 (Hc / Wl+Ob/W2l+zt) | Acomb 16640 = 118272 B.
// ---------------------------------------------------------------------------
__global__ __launch_bounds__(256) void layer_k(const unsigned short* __restrict__ Asb,
                                               const unsigned short* __restrict__ Asqb,
                                               const unsigned short* __restrict__ xf_in,
                                               const unsigned short* __restrict__ HcT_l,
                                               const float* __restrict__ CtT,
                                               const float* __restrict__ W2,
                                               const float* __restrict__ b2,
                                               const float* __restrict__ merge,
                                               unsigned short* __restrict__ xf_out,
                                               float* __restrict__ out,
                                               int wflag) {
    __shared__ char smem[118272];
    __shared__ float CtS[192];
    __shared__ float mlS[8];
    unsigned short* Ablk  = (unsigned short*)smem;              // [8][1552]
    unsigned short* Bs    = (unsigned short*)(smem + 24832);    // Hc [192][200]
    float* Wl             = (float*)(smem + 24832);             // [64][196] (alias)
    unsigned short* Ob    = (unsigned short*)(smem + 75008);    // [8][520]  (alias)
    float* W2l            = (float*)(smem + 75008);             // [64][65]  (alias)
    float* zt             = (float*)(smem + 91648);             // [8][65]   (alias)
    unsigned short* Acomb = (unsigned short*)(smem + 101632);   // [16][520]

    int tid = threadIdx.x;
    int wave = tid >> 6, lane = tid & 63;
    int l16 = lane & 15, quad = lane >> 4;
    int wm = wave & 1, wn = wave >> 1;
    int s0 = blockIdx.x * 8, b = blockIdx.y;

    if (tid < 192) CtS[tid] = CtT[tid];
    if (tid < 8) mlS[tid] = merge[tid];

    // ---- stage: Acomb rows 0-7 = As[s0..], 8-15 = Asq[s0..]
    #pragma unroll
    for (int it = 0; it < 4; ++it) {
        int idx = it * 256 + tid;
        int row = idx >> 6, c = idx & 63;
        const unsigned short* src = (row < 8)
            ? (Asb  + (size_t)(s0 + row) * SP + c * 8)
            : (Asqb + (size_t)(s0 + row - 8) * SP + c * 8);
        *(int4*)&Acomb[row * ACROW + c * 8] = *(const int4*)src;
    }
    // ---- stage: u0 panels (xf rows, transposed) -> Ablk slot 0
    #pragma unroll
    for (int it = 0; it < 2; ++it) {
        int idx = it * 256 + tid;
        int t = idx >> 6, f = idx & 63;
        bf16x8 v = *(const bf16x8*)(xf_in + ((size_t)((b * 8 + t) * FF + f)) * SP + s0);
        #pragma unroll
        for (int s = 0; s < 8; ++s)
            Ablk[s * ABROW + t * 192 + f] = (unsigned short)v[s];
    }
    // ---- stage: Hc
    {
        int br = tid >> 3, bc = tid & 7;
        #pragma unroll
        for (int it = 0; it < 6; ++it) {
            int row = it * 32 + br;
            const unsigned short* hp = HcT_l + (size_t)row * 192;
            #pragma unroll
            for (int j = 0; j < 3; ++j) {
                int c = bc + j * 8;
                *(int4*)&Bs[row * HROW + c * 8] = *(const int4*)(hp + c * 8);
            }
        }
    }
    __syncthreads();

    // ---- phase A: u-GEMM. wave = n-fragment (16 f's); M=16 = [8 u1 | 8 u2].
    {
        #pragma unroll 2
        for (int t = 0; t < 8; ++t) {
            const unsigned short* bb =
                xf_in + ((size_t)((b * 8 + t) * FF + wave * 16 + l16)) * SP + quad * 8;
            floatx4 acc = {};
            #pragma unroll
            for (int ks = 0; ks < 16; ++ks)
                acc = __builtin_amdgcn_mfma_f32_16x16x32_bf16(
                    *(const bf16x8*)&Acomb[l16 * ACROW + ks * 32 + quad * 8],
                    *(const bf16x8*)(bb + ks * 32), acc, 0, 0, 0);
            int f = wave * 16 + l16;
            #pragma unroll
            for (int r = 0; r < 4; ++r) {
                int m = quad * 4 + r;
                int s = m & 7;
                int slot = (m < 8) ? 64 : 128;
                Ablk[s * ABROW + t * 192 + slot + f] = (unsigned short)f2bf(acc[r]);
            }
        }
    }
    __syncthreads();

    // ---- phase B: hmix GEMM (R4 verbatim; A-frags from Ablk LDS)
    floatx4 acc[2][6] = {};
    {
        bf16x8 afr[2][6];
        #pragma unroll
        for (int mt = 0; mt < 2; ++mt) {
            int tp = (wm * 2 + mt) * 2 + (l16 >> 3);
            #pragma unroll
            for (int ks = 0; ks < 6; ++ks)
                afr[mt][ks] = *(const bf16x8*)&Ablk[(l16 & 7) * ABROW + tp * 192 + ks * 32 + quad * 8];
        }
        #pragma unroll
        for (int ks = 0; ks < 6; ++ks) {
            bf16x8 bfr[6];
            #pragma unroll
            for (int nt = 0; nt < 6; ++nt)
                bfr[nt] = *(const bf16x8*)&Bs[((wn * 6 + nt) * 16 + l16) * HROW + ks * 32 + quad * 8];
            #pragma unroll
            for (int mt = 0; mt < 2; ++mt)
                #pragma unroll
                for (int nt = 0; nt < 6; ++nt)
                    acc[mt][nt] = __builtin_amdgcn_mfma_f32_16x16x32_bf16(afr[mt][ks], bfr[nt], acc[mt][nt], 0, 0, 0);
        }
    }
    __syncthreads();   // Hc + Ablk reads done; Wl aliases Hc

    // ---- W -> LDS fp32 (R4 verbatim)
    #pragma unroll
    for (int mt = 0; mt < 2; ++mt)
        #pragma unroll
        for (int nt = 0; nt < 6; ++nt) {
            int col = (wn * 6 + nt) * 16 + l16;
            #pragma unroll
            for (int r = 0; r < 4; ++r) {
                int fr = quad * 4 + r;
                int tp = (wm * 2 + mt) * 2 + (fr >> 3);
                int srow = fr & 7;
                Wl[(tp * 8 + srow) * WROW + col] = acc[mt][nt][r];
            }
        }
    if (!wflag) {
        for (int i = tid; i < 4096; i += 256) { int f = i >> 6, j = i & 63; W2l[j * 65 + f] = W2[i]; }
    }
    __syncthreads();

    // ---- phase C: temporal contraction (R4 verbatim)
    int f = tid & 63, sg = tid >> 6;
    float th[8][2];
    {
        float o[8][2] = {};
        #pragma unroll
        for (int pt = 0; pt < 24; ++pt) {
            int tp = pt & 7, p = pt >> 3;
            float w0 = Wl[(tp * 8 + sg * 2 + 0) * WROW + p * 64 + f];
            float w1 = Wl[(tp * 8 + sg * 2 + 1) * WROW + p * 64 + f];
            #pragma unroll
            for (int t = 0; t < 8; ++t) {
                float cv = CtS[pt * 8 + t];
                o[t][0] += cv * w0;
                o[t][1] += cv * w1;
            }
        }
        #pragma unroll
        for (int t = 0; t < 8; ++t) {
            th[t][0] = ftanh(o[t][0]);
            th[t][1] = ftanh(o[t][1]);
        }
    }

    if (wflag) {
        #pragma unroll
        for (int t = 0; t < 8; ++t) {
            Ob[(sg * 2 + 0) * OROW + t * 64 + f] = (unsigned short)f2bf(th[t][0]);
            Ob[(sg * 2 + 1) * OROW + t * 64 + f] = (unsigned short)f2bf(th[t][1]);
        }
        __syncthreads();
        // xf_out: 16B per (t,f) row
        #pragma unroll
        for (int it = 0; it < 2; ++it) {
            int u = it * 256 + tid;          // [0,512)
            int t = u >> 6, ff = u & 63;
            unsigned short tmp[8];
            #pragma unroll
            for (int sl = 0; sl < 8; ++sl) tmp[sl] = Ob[sl * OROW + t * 64 + ff];
            int4 w;
            w.x = tmp[0] | (tmp[1] << 16); w.y = tmp[2] | (tmp[3] << 16);
            w.z = tmp[4] | (tmp[5] << 16); w.w = tmp[6] | (tmp[7] << 16);
            *(int4*)(xf_out + ((size_t)(b * 8 + t) * FF + ff) * SP + s0) = w;
        }
    } else {
        float z0 = 0.f, z1 = 0.f;
        #pragma unroll
        for (int t = 0; t < 8; ++t) {
            z0 += mlS[t] * th[t][0];
            z1 += mlS[t] * th[t][1];
        }
        zt[(sg * 2 + 0) * 65 + f] = z0;
        zt[(sg * 2 + 1) * 65 + f] = z1;
        __syncthreads();
        float msum = 0.f;
        #pragma unroll
        for (int t = 0; t < 8; ++t) msum += mlS[t];
        float bv = b2[f] * msum;
        #pragma unroll
        for (int r = 0; r < 2; ++r) {
            int s = s0 + sg * 2 + r;
            if (s < SS) {
                float accv = bv;
                #pragma unroll
                for (int j = 0; j < FF; ++j) accv += zt[(sg * 2 + r) * 65 + j] * W2l[j * 65 + f];
                out[((size_t)b * SS + s) * FF + f] = accv;
            }
        }
    }
}

// ---------------------------------------------------------------------------
extern "C" void kernel_launch(void* const* d_in, const int* in_sizes, int n_in,
                              void* d_out, int out_size, void* d_ws, size_t ws_size,
                              hipStream_t stream) {
    const float* x     = (const float*)d_in[0];
    const float* At    = (const float*)d_in[1];
    const float* As    = (const float*)d_in[2];
    const float* sc    = (const float*)d_in[3];
    const float* H     = (const float*)d_in[4];
    const float* W1    = (const float*)d_in[5];
    const float* b1    = (const float*)d_in[6];
    const float* W2    = (const float*)d_in[7];
    const float* b2    = (const float*)d_in[8];
    const float* merge = (const float*)d_in[9];
    float* out = (float*)d_out;

    char* ws = (char*)d_ws;
    unsigned short* Asb   = (unsigned short*)(ws + 0);          // 524288
    unsigned short* AsbT  = (unsigned short*)(ws + 524288);     // 524288
    unsigned short* Asqb  = (unsigned short*)(ws + 1048576);    // 524288
    unsigned short* HcT   = (unsigned short*)(ws + 1572864);    // 221184
    float*          CtT   = (float*)(ws + 1794048);             // 768
    unsigned short* xfT0  = (unsigned short*)(ws + 6291456);    // 4194304
    unsigned short* xfT1  = (unsigned short*)(ws + 10485760);   // 4194304

    setup_k<<<2993, 256, 0, stream>>>(x, W1, b1, As, At, sc, H,
                                      Asb, AsbT, HcT, CtT, xfT0);
    prep2_k<<<dim3(32, 8), 256, 0, stream>>>(Asb, AsbT, Asqb);

    unsigned short* xf_cur = xfT0;  unsigned short* xf_nxt = xfT1;
    for (int l = 0; l < 3; ++l) {
        layer_k<<<dim3(64, 8), 256, 0, stream>>>(Asb, Asqb, xf_cur,
                                                 HcT + (size_t)l * 36864, CtT,
                                                 W2, b2, merge,
                                                 xf_nxt, out, (l < 2) ? 1 : 0);
        unsigned short* tt = xf_cur; xf_cur = xf_nxt; xf_nxt = tt;
    }
}

// Round 12
// 229.274 us; speedup vs baseline: 5.2763x; 1.0033x over previous
//
#include <hip/hip_runtime.h>

// B=8, T=8, S=500 (padded 512), F_IN=32, F=F_OUT=64, K=3, L=3
#define BB 8
#define TT 8
#define SS 500
#define SP 512
#define FIN 32
#define FF 64
#define HROW 200      // Hc LDS row stride in shorts (192 + 8)
#define WROW 196      // W row stride in floats (192 + 4)
#define OROW 520      // Ob row stride in shorts (512 + 8)
#define ABROW 1544    // Ablk row stride in shorts (1536 + 8): 772 dw ≡ 4 mod 32
                      //   -> phase-B row reads spread all 8 bank groups (was 2x-aliased at 1552)

typedef short bf16x8 __attribute__((ext_vector_type(8)));
typedef float floatx4 __attribute__((ext_vector_type(4)));

__device__ __forceinline__ unsigned f2bf(float x) {
    unsigned u = __builtin_bit_cast(unsigned, x);
    return (u + 0x7FFFu + ((u >> 16) & 1u)) >> 16;   // RNE bf16 in low 16
}
__device__ __forceinline__ float ftanh(float x) {
    float ax = fabsf(x);
    float e = __expf(-2.f * ax);
    float r = (1.f - e) * __builtin_amdgcn_rcpf(1.f + e);
    return copysignf(r, x);
}

__device__ __forceinline__ void ctab(int m, float s0, float s1, float s2, float s3,
                                     float& c0, float& c1, float& c2) {
    c0 = 0.f; c1 = 0.f; c2 = 0.f;
    switch (m) {
        case 0: c0 = 1.f; c1 = s0; c2 = s0 * s0; break;
        case 1: c1 = s1; c2 = 2.f * s0 * s1; break;
        case 2: c2 = s1 * s1; break;
        case 3: c1 = s2; c2 = 2.f * s0 * s2; break;
        case 4: c1 = s3; c2 = 2.f * (s0 * s3 + s1 * s2); break;
        case 5: c2 = 2.f * s1 * s3; break;
        case 6: c2 = s2 * s2; break;
        case 7: c2 = 2.f * s2 * s3; break;
        case 8: c2 = s3 * s3; break;
    }
}

// ---------------------------------------------------------------------------
// setup_k: blocks [0,512): lin1 -> xfT only; blocks [512,...): Asb/AsbT+HcT+CtT
// ---------------------------------------------------------------------------
__global__ __launch_bounds__(256) void setup_k(const float* __restrict__ x,
                                               const float* __restrict__ W1,
                                               const float* __restrict__ b1,
                                               const float* __restrict__ As,
                                               const float* __restrict__ At,
                                               const float* __restrict__ sc,
                                               const float* __restrict__ H,
                                               unsigned short* __restrict__ Asb,
                                               unsigned short* __restrict__ AsbT,
                                               unsigned short* __restrict__ HcT,
                                               float* __restrict__ CtT,
                                               unsigned short* __restrict__ xfT) {
    int tid = threadIdx.x;
    if (blockIdx.x < 512) {
        __shared__ float Xs[64][FIN + 1];
        __shared__ float Wl[FIN][FF];
        __shared__ float Ot[64][FF + 1];
        __shared__ float bl[FF];
        int bt = blockIdx.x >> 3, s0 = (blockIdx.x & 7) * 64;

        for (int i = tid; i < FIN * FF; i += 256) { int f = i >> 5, j = i & 31; Wl[j][f] = W1[i]; }
        if (tid < FF) bl[tid] = b1[tid];
        const float* xb = x + (size_t)bt * SS * FIN;
        #pragma unroll
        for (int i = 0; i < 8; ++i) {
            int lin = i * 256 + tid; int r = lin >> 5, j = lin & 31;
            int s = s0 + r;
            Xs[r][j] = (s < SS) ? xb[(size_t)s * FIN + j] : 0.f;
        }
        __syncthreads();
        int f = tid & 63, sq = tid >> 6;
        for (int i = 0; i < 16; ++i) {
            int r = sq * 16 + i;
            float acc = bl[f];
            #pragma unroll
            for (int j = 0; j < FIN; ++j) acc += Xs[r][j] * Wl[j][f];
            Ot[r][f] = (s0 + r < SS) ? acc : 0.f;
        }
        __syncthreads();
        // transposed write: xfT[bt][f][s]
        {
            int ff = tid >> 2, scol = (tid & 3) * 16;
            unsigned short tmp[16];
            #pragma unroll
            for (int i = 0; i < 16; ++i) tmp[i] = (unsigned short)f2bf(Ot[scol + i][ff]);
            unsigned short* dp = xfT + ((size_t)bt * FF + ff) * SP + s0 + scol;
            #pragma unroll
            for (int q = 0; q < 2; ++q) {
                int4 w;
                w.x = tmp[q*8+0] | (tmp[q*8+1] << 16); w.y = tmp[q*8+2] | (tmp[q*8+3] << 16);
                w.z = tmp[q*8+4] | (tmp[q*8+5] << 16); w.w = tmp[q*8+6] | (tmp[q*8+7] << 16);
                *(int4*)(dp + q * 8) = w;
            }
        }
        return;
    }
    int idx = (blockIdx.x - 512) * 256 + tid;
    if (idx < 262144) {
        int s = idx >> 9, k = idx & 511;
        Asb[idx] = (s < SS && k < SS) ? (unsigned short)f2bf(As[(size_t)s * SS + k]) : 0;
    } else if (idx < 524288) {
        int r = idx - 262144;
        int j = r >> 9, k = r & 511;
        AsbT[r] = (j < SS && k < SS) ? (unsigned short)f2bf(As[(size_t)k * SS + j]) : 0;
    } else {
        int r = idx - 524288;
        if (r < 110592) {
            int l = r / 36864;
            int r2 = r - l * 36864;
            int row = r2 / 192;
            int col = r2 - row * 192;
            int p = row >> 6, f = row & 63;
            int bp = col >> 6, j = col & 63;
            float s0 = sc[0], s1 = sc[1], s2 = sc[2], s3 = sc[3];
            float c0, c1, c2;
            ctab(p * 3 + bp, s0, s1, s2, s3, c0, c1, c2);
            float val = c0 * H[((size_t)(l * 3 + 0) * 64 + j) * 64 + f]
                      + c1 * H[((size_t)(l * 3 + 1) * 64 + j) * 64 + f]
                      + c2 * H[((size_t)(l * 3 + 2) * 64 + j) * 64 + f];
            HcT[r] = (unsigned short)f2bf(val);
        } else if (r < 110784) {
            int i2 = r - 110592;
            int pt = i2 >> 3, t = i2 & 7;
            int p = pt >> 3, tp = pt & 7;
            float val;
            if (p == 0) val = (t == tp) ? 1.f : 0.f;
            else if (p == 1) val = At[t * 8 + tp];
            else {
                val = 0.f;
                #pragma unroll
                for (int kk = 0; kk < 8; ++kk) val += At[t * 8 + kk] * At[kk * 8 + tp];
            }
            CtT[i2] = val;
        }
    }
}

// ---------------------------------------------------------------------------
// prep2: Asqb = (As@As) bf16 [512][512]  (unchanged, R4-verified)
// ---------------------------------------------------------------------------
__global__ __launch_bounds__(256) void prep2_k(const unsigned short* __restrict__ Asb,
                                               const unsigned short* __restrict__ AsbT,
                                               unsigned short* __restrict__ Asqb) {
    int tid = threadIdx.x;
    int wave = tid >> 6, lane = tid & 63;
    int l16 = lane & 15, quad = lane >> 4;
    int st = blockIdx.x, ct = blockIdx.y;

    const unsigned short* ap = Asb + (size_t)(st * 16 + l16) * SP + quad * 8;
    const unsigned short* bp = AsbT + (size_t)(ct * 64 + wave * 16 + l16) * SP + quad * 8;
    floatx4 acc = {};
    #pragma unroll 4
    for (int k0 = 0; k0 < SP; k0 += 32)
        acc = __builtin_amdgcn_mfma_f32_16x16x32_bf16(*(const bf16x8*)(ap + k0),
                                                      *(const bf16x8*)(bp + k0), acc, 0, 0, 0);
    int j = ct * 64 + wave * 16 + l16;
    int i0 = st * 16 + quad * 4;
    #pragma unroll
    for (int r = 0; r < 4; ++r)
        Asqb[(size_t)(i0 + r) * SP + j] = (unsigned short)f2bf(acc[r]);
}

// ---------------------------------------------------------------------------
// layer_k v2: fused smm+hmix(+zred on last). Flat grid 512.
//   XCD swizzle: b = bid&7 (round-robin -> all blocks sharing a b-panel of xf
//   land on ONE XCD -> panel L2-resident; kills the 4x HBM refetch).
//   Phase A A-frags per-lane DIRECT from As/Asq global (L2-hot, t-invariant,
//   hoisted to 16 regs) -- Acomb LDS deleted.
//   ABROW 1544: phase-B row reads conflict-free; u-writes 8->4-way.
// LDS: Ablk [8][1544] 24704 | region2 76800 (Hc / Wl+Ob / W2l+zt) = 101504 B.
// ---------------------------------------------------------------------------
__global__ __launch_bounds__(256) void layer_k(const unsigned short* __restrict__ Asb,
                                               const unsigned short* __restrict__ Asqb,
                                               const unsigned short* __restrict__ xf_in,
                                               const unsigned short* __restrict__ HcT_l,
                                               const float* __restrict__ CtT,
                                               const float* __restrict__ W2,
                                               const float* __restrict__ b2,
                                               const float* __restrict__ merge,
                                               unsigned short* __restrict__ xf_out,
                                               float* __restrict__ out,
                                               int wflag) {
    __shared__ char smem[101504];
    __shared__ float CtS[192];
    __shared__ float mlS[8];
    unsigned short* Ablk  = (unsigned short*)smem;              // [8][1544]
    unsigned short* Bs    = (unsigned short*)(smem + 24704);    // Hc [192][200]
    float* Wl             = (float*)(smem + 24704);             // [64][196] (alias)
    unsigned short* Ob    = (unsigned short*)(smem + 74880);    // [8][520]  (alias)
    float* W2l            = (float*)(smem + 74880);             // [64][65]  (alias)
    float* zt             = (float*)(smem + 91520);             // [8][65]   (alias)

    int tid = threadIdx.x;
    int wave = tid >> 6, lane = tid & 63;
    int l16 = lane & 15, quad = lane >> 4;
    int wm = wave & 1, wn = wave >> 1;
    int b = blockIdx.x & 7;              // XCD-aware: same-b blocks -> same XCD
    int s0 = (blockIdx.x >> 3) * 8;

    if (tid < 192) CtS[tid] = CtT[tid];
    if (tid < 8) mlS[tid] = merge[tid];

    // ---- stage: u0 panels (xf rows, transposed) -> Ablk slot 0
    #pragma unroll
    for (int it = 0; it < 2; ++it) {
        int idx = it * 256 + tid;
        int t = idx >> 6, f = idx & 63;
        bf16x8 v = *(const bf16x8*)(xf_in + ((size_t)((b * 8 + t) * FF + f)) * SP + s0);
        #pragma unroll
        for (int s = 0; s < 8; ++s)
            Ablk[s * ABROW + t * 192 + f] = (unsigned short)v[s];
    }
    // ---- stage: Hc
    {
        int br = tid >> 3, bc = tid & 7;
        #pragma unroll
        for (int it = 0; it < 6; ++it) {
            int row = it * 32 + br;
            const unsigned short* hp = HcT_l + (size_t)row * 192;
            #pragma unroll
            for (int j = 0; j < 3; ++j) {
                int c = bc + j * 8;
                *(int4*)&Bs[row * HROW + c * 8] = *(const int4*)(hp + c * 8);
            }
        }
    }
    // (no barrier needed here: phase A reads only globals; the post-phase-A
    //  barrier orders all LDS staging before phase B's reads)

    // ---- phase A: u-GEMM. A-frag row l16 = As(s0+l16) [l16<8] / Asq [l16>=8],
    //      hoisted t-invariant into 16 regs. wave = n-fragment (16 f's).
    {
        const unsigned short* arow =
            ((l16 < 8) ? Asb : Asqb) + (size_t)(s0 + (l16 & 7)) * SP + quad * 8;
        bf16x8 areg[16];
        #pragma unroll
        for (int ks = 0; ks < 16; ++ks) areg[ks] = *(const bf16x8*)(arow + ks * 32);

        #pragma unroll 2
        for (int t = 0; t < 8; ++t) {
            const unsigned short* bb =
                xf_in + ((size_t)((b * 8 + t) * FF + wave * 16 + l16)) * SP + quad * 8;
            floatx4 acc = {};
            #pragma unroll
            for (int ks = 0; ks < 16; ++ks)
                acc = __builtin_amdgcn_mfma_f32_16x16x32_bf16(
                    areg[ks], *(const bf16x8*)(bb + ks * 32), acc, 0, 0, 0);
            int f = wave * 16 + l16;
            #pragma unroll
            for (int r = 0; r < 4; ++r) {
                int m = quad * 4 + r;
                int s = m & 7;
                int slot = (m < 8) ? 64 : 128;
                Ablk[s * ABROW + t * 192 + slot + f] = (unsigned short)f2bf(acc[r]);
            }
        }
    }
    __syncthreads();

    // ---- phase B: hmix GEMM (A-frags from Ablk LDS, B from Hc LDS)
    floatx4 acc[2][6] = {};
    {
        bf16x8 afr[2][6];
        #pragma unroll
        for (int mt = 0; mt < 2; ++mt) {
            int tp = (wm * 2 + mt) * 2 + (l16 >> 3);
            #pragma unroll
            for (int ks = 0; ks < 6; ++ks)
                afr[mt][ks] = *(const bf16x8*)&Ablk[(l16 & 7) * ABROW + tp * 192 + ks * 32 + quad * 8];
        }
        #pragma unroll
        for (int ks = 0; ks < 6; ++ks) {
            bf16x8 bfr[6];
            #pragma unroll
            for (int nt = 0; nt < 6; ++nt)
                bfr[nt] = *(const bf16x8*)&Bs[((wn * 6 + nt) * 16 + l16) * HROW + ks * 32 + quad * 8];
            #pragma unroll
            for (int mt = 0; mt < 2; ++mt)
                #pragma unroll
                for (int nt = 0; nt < 6; ++nt)
                    acc[mt][nt] = __builtin_amdgcn_mfma_f32_16x16x32_bf16(afr[mt][ks], bfr[nt], acc[mt][nt], 0, 0, 0);
        }
    }
    __syncthreads();   // Hc + Ablk reads done; Wl aliases Hc

    // ---- W -> LDS fp32
    #pragma unroll
    for (int mt = 0; mt < 2; ++mt)
        #pragma unroll
        for (int nt = 0; nt < 6; ++nt) {
            int col = (wn * 6 + nt) * 16 + l16;
            #pragma unroll
            for (int r = 0; r < 4; ++r) {
                int fr = quad * 4 + r;
                int tp = (wm * 2 + mt) * 2 + (fr >> 3);
                int srow = fr & 7;
                Wl[(tp * 8 + srow) * WROW + col] = acc[mt][nt][r];
            }
        }
    if (!wflag) {
        for (int i = tid; i < 4096; i += 256) { int f = i >> 6, j = i & 63; W2l[j * 65 + f] = W2[i]; }
    }
    __syncthreads();

    // ---- phase C: temporal contraction
    int f = tid & 63, sg = tid >> 6;
    float th[8][2];
    {
        float o[8][2] = {};
        #pragma unroll
        for (int pt = 0; pt < 24; ++pt) {
            int tp = pt & 7, p = pt >> 3;
            float w0 = Wl[(tp * 8 + sg * 2 + 0) * WROW + p * 64 + f];
            float w1 = Wl[(tp * 8 + sg * 2 + 1) * WROW + p * 64 + f];
            #pragma unroll
            for (int t = 0; t < 8; ++t) {
                float cv = CtS[pt * 8 + t];
                o[t][0] += cv * w0;
                o[t][1] += cv * w1;
            }
        }
        #pragma unroll
        for (int t = 0; t < 8; ++t) {
            th[t][0] = ftanh(o[t][0]);
            th[t][1] = ftanh(o[t][1]);
        }
    }

    if (wflag) {
        #pragma unroll
        for (int t = 0; t < 8; ++t) {
            Ob[(sg * 2 + 0) * OROW + t * 64 + f] = (unsigned short)f2bf(th[t][0]);
            Ob[(sg * 2 + 1) * OROW + t * 64 + f] = (unsigned short)f2bf(th[t][1]);
        }
        __syncthreads();
        // xf_out: 16B per (t,f) row
        #pragma unroll
        for (int it = 0; it < 2; ++it) {
            int u = it * 256 + tid;          // [0,512)
            int t = u >> 6, ff = u & 63;
            unsigned short tmp[8];
            #pragma unroll
            for (int sl = 0; sl < 8; ++sl) tmp[sl] = Ob[sl * OROW + t * 64 + ff];
            int4 w;
            w.x = tmp[0] | (tmp[1] << 16); w.y = tmp[2] | (tmp[3] << 16);
            w.z = tmp[4] | (tmp[5] << 16); w.w = tmp[6] | (tmp[7] << 16);
            *(int4*)(xf_out + ((size_t)(b * 8 + t) * FF + ff) * SP + s0) = w;
        }
    } else {
        float z0 = 0.f, z1 = 0.f;
        #pragma unroll
        for (int t = 0; t < 8; ++t) {
            z0 += mlS[t] * th[t][0];
            z1 += mlS[t] * th[t][1];
        }
        zt[(sg * 2 + 0) * 65 + f] = z0;
        zt[(sg * 2 + 1) * 65 + f] = z1;
        __syncthreads();
        float msum = 0.f;
        #pragma unroll
        for (int t = 0; t < 8; ++t) msum += mlS[t];
        float bv = b2[f] * msum;
        #pragma unroll
        for (int r = 0; r < 2; ++r) {
            int s = s0 + sg * 2 + r;
            if (s < SS) {
                float accv = bv;
                #pragma unroll
                for (int j = 0; j < FF; ++j) accv += zt[(sg * 2 + r) * 65 + j] * W2l[j * 65 + f];
                out[((size_t)b * SS + s) * FF + f] = accv;
            }
        }
    }
}

// ---------------------------------------------------------------------------
extern "C" void kernel_launch(void* const* d_in, const int* in_sizes, int n_in,
                              void* d_out, int out_size, void* d_ws, size_t ws_size,
                              hipStream_t stream) {
    const float* x     = (const float*)d_in[0];
    const float* At    = (const float*)d_in[1];
    const float* As    = (const float*)d_in[2];
    const float* sc    = (const float*)d_in[3];
    const float* H     = (const float*)d_in[4];
    const float* W1    = (const float*)d_in[5];
    const float* b1    = (const float*)d_in[6];
    const float* W2    = (const float*)d_in[7];
    const float* b2    = (const float*)d_in[8];
    const float* merge = (const float*)d_in[9];
    float* out = (float*)d_out;

    char* ws = (char*)d_ws;
    unsigned short* Asb   = (unsigned short*)(ws + 0);          // 524288
    unsigned short* AsbT  = (unsigned short*)(ws + 524288);     // 524288
    unsigned short* Asqb  = (unsigned short*)(ws + 1048576);    // 524288
    unsigned short* HcT   = (unsigned short*)(ws + 1572864);    // 221184
    float*          CtT   = (float*)(ws + 1794048);             // 768
    unsigned short* xfT0  = (unsigned short*)(ws + 6291456);    // 4194304
    unsigned short* xfT1  = (unsigned short*)(ws + 10485760);   // 4194304

    setup_k<<<2993, 256, 0, stream>>>(x, W1, b1, As, At, sc, H,
                                      Asb, AsbT, HcT, CtT, xfT0);
    prep2_k<<<dim3(32, 8), 256, 0, stream>>>(Asb, AsbT, Asqb);

    unsigned short* xf_cur = xfT0;  unsigned short* xf_nxt = xfT1;
    for (int l = 0; l < 3; ++l) {
        layer_k<<<512, 256, 0, stream>>>(Asb, Asqb, xf_cur,
                                         HcT + (size_t)l * 36864, CtT,
                                         W2, b2, merge,
                                         xf_nxt, out, (l < 2) ? 1 : 0);
        unsigned short* tt = xf_cur; xf_cur = xf_nxt; xf_nxt = tt;
    }
}